// Round 7
// baseline (757.966 us; speedup 1.0000x reference)
//
#include <hip/hip_runtime.h>
#include <hip/hip_bf16.h>
#include <math.h>

#define DMODEL 2048
#define SEQ    2048
#define NH     32
#define NG     8
#define DH     64

typedef unsigned short u16;
using v8bf  = __attribute__((ext_vector_type(8))) __bf16;
using f32x4 = __attribute__((ext_vector_type(4))) float;

__device__ __forceinline__ float bf2f(u16 u) {
    unsigned int x = ((unsigned int)u) << 16;
    return __uint_as_float(x);
}
__device__ __forceinline__ u16 f2bf(float f) {
    unsigned int x = __float_as_uint(f);
    unsigned int r = (x + 0x7fffu + ((x >> 16) & 1u)) >> 16;
    return (u16)r;
}
__device__ __forceinline__ f32x4 mfma16(v8bf a, v8bf b, f32x4 c) {
    return __builtin_amdgcn_mfma_f32_16x16x32_bf16(a, b, c, 0, 0, 0);
}

#define LOG1E4_64 0.14391156509880297f
#define LOG2E     1.4426950408889634f

// ws layout (u16 element offsets). Weights TRANSPOSED [n][k]. RoPE table
// overlaps ctx (written by rope_table, consumed by gemm_qkv, then attn
// overwrites with ctx — stream-ordered). Footprint = R3-proven 79,695,872 B.
#define C_HS   0u
#define C_WQ   8388608u
#define C_WK   12582912u
#define C_WV   13631488u
#define C_WO   14680064u
#define C_BO   18874368u
#define W_Q    18876416u   // [b,h][s][d]
#define W_K    27265024u   // [b,g][s][d]
#define W_V    29362176u   // [b,g][d][s]
#define W_CTX  31459328u   // [b,s][h*64+d] (also transient RoPE table)

// ---------------------------------------------------------------------------
// Runtime input-dtype detection (R3-verified).
// ---------------------------------------------------------------------------
__device__ __forceinline__ bool detect_is_f32(const u16* hsu, int tid, float* red)
{
    ushort4 a = *(const ushort4*)(hsu + tid * 8);
    ushort4 b = *(const ushort4*)(hsu + tid * 8 + 4);
    u16 vals[8] = {a.x, a.y, a.z, a.w, b.x, b.y, b.z, b.w};
    float mymax = 0.0f;
    #pragma unroll
    for (int e = 0; e < 8; ++e) {
        float av = fabsf(bf2f(vals[e]));
        if (!(av < 1.0e30f)) av = 1.0e30f;
        mymax = fmaxf(mymax, av);
    }
    #pragma unroll
    for (int off = 1; off < 64; off <<= 1)
        mymax = fmaxf(mymax, __shfl_xor(mymax, off, 64));
    if ((tid & 63) == 0) red[tid >> 6] = mymax;
    __syncthreads();
    float m = fmaxf(fmaxf(red[0], red[1]), fmaxf(red[2], red[3]));
    __syncthreads();
    return m > 1.0e6f;
}

// ---------------------------------------------------------------------------
// Prelude A: convert hs + bo to canonical bf16.
// ---------------------------------------------------------------------------
__global__ __launch_bounds__(256)
void conv_hs_bo(const void* __restrict__ hs, const void* __restrict__ bo,
                u16* __restrict__ canon)
{
    __shared__ float red[4];
    const int tid = threadIdx.x;
    const bool is_f32 = detect_is_f32((const u16*)hs, tid, red);
    unsigned int g = (blockIdx.x * 256u + tid) * 8u;
    const void* src; unsigned int loc; u16* dst;
    if (g < 8388608u) { src = hs; loc = g;            dst = canon + C_HS + g; }
    else              { src = bo; loc = g - 8388608u; dst = canon + C_BO + loc; }

    ushort4 o0, o1;
    if (is_f32) {
        const float* f = (const float*)src + loc;
        float4 x = *(const float4*)f;
        float4 y = *(const float4*)(f + 4);
        o0.x = f2bf(x.x); o0.y = f2bf(x.y); o0.z = f2bf(x.z); o0.w = f2bf(x.w);
        o1.x = f2bf(y.x); o1.y = f2bf(y.y); o1.z = f2bf(y.z); o1.w = f2bf(y.w);
    } else {
        const u16* u = (const u16*)src + loc;
        o0 = *(const ushort4*)u;
        o1 = *(const ushort4*)(u + 4);
    }
    *(ushort4*)dst       = o0;
    *(ushort4*)(dst + 4) = o1;
}

// ---------------------------------------------------------------------------
// Prelude B: tiled transpose-convert of weight (K x N) -> bf16 [n][k].
// ---------------------------------------------------------------------------
__global__ __launch_bounds__(256)
void transp_w(const void* __restrict__ W, u16* __restrict__ dst,
              int K, int N, const u16* __restrict__ hs_orig)
{
    __shared__ float red[4];
    __shared__ u16 Ts[64][68];
    const int tid = threadIdx.x;
    const bool is_f32 = detect_is_f32(hs_orig, tid, red);
    const int n0 = blockIdx.x * 64, k0 = blockIdx.y * 64;

    #pragma unroll
    for (int it = 0; it < 4; ++it) {
        int e  = tid + it * 256;
        int kr = e >> 4, n4 = (e & 15) << 2;
        if (is_f32) {
            const float* s = (const float*)W + (size_t)(k0 + kr) * N + n0 + n4;
            float4 x = *(const float4*)s;
            Ts[n4+0][kr] = f2bf(x.x); Ts[n4+1][kr] = f2bf(x.y);
            Ts[n4+2][kr] = f2bf(x.z); Ts[n4+3][kr] = f2bf(x.w);
        } else {
            ushort4 u = *(const ushort4*)((const u16*)W + (size_t)(k0 + kr) * N + n0 + n4);
            Ts[n4+0][kr] = u.x; Ts[n4+1][kr] = u.y;
            Ts[n4+2][kr] = u.z; Ts[n4+3][kr] = u.w;
        }
    }
    __syncthreads();
    #pragma unroll
    for (int it = 0; it < 4; ++it) {
        int e  = tid + it * 256;
        int nr = e >> 4, k4 = (e & 15) << 2;
        ushort4 u;
        u.x = Ts[nr][k4+0]; u.y = Ts[nr][k4+1];
        u.z = Ts[nr][k4+2]; u.w = Ts[nr][k4+3];
        *(ushort4*)(dst + (size_t)(n0 + nr) * K + k0 + k4) = u;
    }
}

// ---------------------------------------------------------------------------
// Prelude C: RoPE table (precise sincosf; angles to 2047 rad).
// ---------------------------------------------------------------------------
__global__ __launch_bounds__(256)
void rope_table(float* __restrict__ c, float* __restrict__ s)
{
    int idx = blockIdx.x * 256 + threadIdx.x;     // 131072 total
    int sq = idx >> 6, d = idx & 63;
    float freq = expf(-(float)(d & ~1) * LOG1E4_64);
    float sn, cs;
    sincosf((float)sq * freq, &sn, &cs);
    c[idx] = cs; s[idx] = sn;
}

// ---------------------------------------------------------------------------
// Kernel 1: QKV projection (MFMA) + RoPE epilogue. (unchanged, R5-passing)
// ---------------------------------------------------------------------------
__global__ __launch_bounds__(256)
void gemm_qkv(const u16* __restrict__ hs, const u16* __restrict__ wqt,
              const u16* __restrict__ wkt, const u16* __restrict__ wvt,
              const float* __restrict__ ropec, const float* __restrict__ ropes,
              u16* __restrict__ qws, u16* __restrict__ kws, u16* __restrict__ vws)
{
    __shared__ __align__(16) u16 As[128][72];
    __shared__ __align__(16) u16 Bs[64][72];
    const int tid = threadIdx.x;
    const int w = tid >> 6, lane = tid & 63;
    const int l15 = lane & 15, quad = lane >> 4;
    const int row0 = blockIdx.x * 128;
    const int n0   = blockIdx.y * 64;

    const u16* Wt; int nb, mode;
    if (n0 < 2048)      { Wt = wqt; nb = n0;        mode = 0; }
    else if (n0 < 2560) { Wt = wkt; nb = n0 - 2048; mode = 1; }
    else                { Wt = wvt; nb = n0 - 2560; mode = 2; }

    f32x4 acc[2][4];
    #pragma unroll
    for (int mt = 0; mt < 2; ++mt)
        #pragma unroll
        for (int nt = 0; nt < 4; ++nt)
            acc[mt][nt] = (f32x4){0.f, 0.f, 0.f, 0.f};

    for (int k0 = 0; k0 < DMODEL; k0 += 64) {
        __syncthreads();
        #pragma unroll
        for (int it = 0; it < 8; ++it) {
            int e = tid + it * 256;
            int m = e >> 4, k4 = (e & 15) << 2;
            *(ushort4*)&As[m][k4] = *(const ushort4*)(hs + (size_t)(row0 + m) * DMODEL + k0 + k4);
        }
        #pragma unroll
        for (int it = 0; it < 4; ++it) {
            int e = tid + it * 256;
            int nr = e >> 4, k4 = (e & 15) << 2;
            *(ushort4*)&Bs[nr][k4] = *(const ushort4*)(Wt + (size_t)(nb + nr) * DMODEL + k0 + k4);
        }
        __syncthreads();
        #pragma unroll
        for (int ks = 0; ks < 2; ++ks) {
            v8bf a[2], b[4];
            #pragma unroll
            for (int mt = 0; mt < 2; ++mt)
                a[mt] = *(const v8bf*)&As[32*w + 16*mt + l15][ks*32 + quad*8];
            #pragma unroll
            for (int nt = 0; nt < 4; ++nt)
                b[nt] = *(const v8bf*)&Bs[16*nt + l15][ks*32 + quad*8];
            #pragma unroll
            for (int mt = 0; mt < 2; ++mt)
                #pragma unroll
                for (int nt = 0; nt < 4; ++nt)
                    acc[mt][nt] = mfma16(a[mt], b[nt], acc[mt][nt]);
        }
    }

    #pragma unroll
    for (int mt = 0; mt < 2; ++mt) {
        #pragma unroll
        for (int nt = 0; nt < 4; ++nt) {
            int col  = n0 + 16*nt + l15;
            int dcol = col & 63;
            #pragma unroll
            for (int reg = 0; reg < 4; ++reg) {
                int row = row0 + 32*w + 16*mt + quad*4 + reg;
                int b = row >> 11, s = row & (SEQ - 1);
                float val = acc[mt][nt][reg];
                if (mode < 2) {   // RoPE (pairs sit in adjacent lanes)
                    float c2 = ropec[(s << 6) + dcol];
                    float s2 = ropes[(s << 6) + dcol];
                    float partner = __shfl_xor(val, 1, 64);
                    val = (dcol & 1) ? (val * c2 + partner * s2)
                                     : (val * c2 - partner * s2);
                }
                if (mode == 0) {
                    int h = col >> 6;
                    qws[((size_t)((b*NH + h) * SEQ + s)) * DH + dcol] = f2bf(val);
                } else if (mode == 1) {
                    int g = (col - 2048) >> 6;
                    kws[((size_t)((b*NG + g) * SEQ + s)) * DH + dcol] = f2bf(val);
                } else {
                    int g = (col - 2560) >> 6;
                    vws[((size_t)((b*NG + g) * DH + dcol)) * SEQ + s] = f2bf(val);
                }
            }
        }
    }
}

// ---------------------------------------------------------------------------
// Kernel 2: flash attention, barrier-free. Fixed-max softmax p=exp(s-30)
// (s bounded by 30*tanh), fused activation exp(-60/(e^{x/15}+1)), direct
// global fragment loads, wave-private P round-trip. R6 bug fixed: Q A-frag
// load now includes the per-quad k-offset (+ ks*32 + quad*8).
// ---------------------------------------------------------------------------
__global__ __launch_bounds__(256)
void attn(const u16* __restrict__ qws, const u16* __restrict__ kws,
          const u16* __restrict__ vws, u16* __restrict__ ctx)
{
    __shared__ __align__(16) u16 Ps[4][16][72];   // wave-private P
    const int tid = threadIdx.x;
    const int w = tid >> 6, lane = tid & 63;
    const int l15 = lane & 15, quad = lane >> 4;
    const int qt = (SEQ/64 - 1) - blockIdx.x;     // long blocks first (tail)
    const int h = blockIdx.y, b = blockIdx.z;
    const int g  = h >> 2;
    const int q0 = qt * 64;

    const float slope = exp2f(-0.25f * (float)(h + 1));
    const u16* qbase  = qws + (size_t)(b*NH + h) * SEQ * DH;
    const u16* kbase  = kws + (size_t)(b*NG + g) * SEQ * DH;
    const u16* vtbase = vws + (size_t)(b*NG + g) * DH * SEQ;   // [d][s]

    // Q A-frags in registers: A[m=l15][k=ks*32+quad*8+j], rows q0+16w+l15
    const u16* qrow = qbase + (size_t)(q0 + 16*w + l15) * DH;
    v8bf qa[2];
    qa[0] = *(const v8bf*)(qrow + 0*32 + quad*8);   // R6 FIX: + quad*8
    qa[1] = *(const v8bf*)(qrow + 1*32 + quad*8);

    // exp2-space constants: arg = sv * (log2e/15); sv = (s_raw - slope*(q-k))/8
    const float Ac = 0.125f * (LOG2E / 15.0f);
    const float Bc = -slope * 0.125f * (LOG2E / 15.0f);
    const float C3 = -60.0f * LOG2E;
    float bd[4][4];
    #pragma unroll
    for (int nt = 0; nt < 4; ++nt)
        #pragma unroll
        for (int reg = 0; reg < 4; ++reg)
            bd[nt][reg] = Bc * (float)((16*w + 4*quad + reg) - (16*nt + l15));

    f32x4 o[4];
    #pragma unroll
    for (int dt = 0; dt < 4; ++dt) o[dt] = (f32x4){0.f, 0.f, 0.f, 0.f};
    float lrow[4] = {0.f, 0.f, 0.f, 0.f};

    for (int kt = 0; kt <= qt; ++kt) {
        const int k0 = kt * 64;

        // K frags: B[n=kpos][k=d] — contiguous in kws [s][d]
        // V frags: B[n=d][k=kpos] — contiguous in vws [d][s]
        v8bf kf[2][4], vf[2][4];
        #pragma unroll
        for (int ks = 0; ks < 2; ++ks)
            #pragma unroll
            for (int nt = 0; nt < 4; ++nt)
                kf[ks][nt] = *(const v8bf*)(kbase + (size_t)(k0 + 16*nt + l15) * DH + ks*32 + quad*8);
        #pragma unroll
        for (int ks = 0; ks < 2; ++ks)
            #pragma unroll
            for (int dt = 0; dt < 4; ++dt)
                vf[ks][dt] = *(const v8bf*)(vtbase + (size_t)(16*dt + l15) * SEQ + k0 + ks*32 + quad*8);

        f32x4 sacc[4];
        #pragma unroll
        for (int nt = 0; nt < 4; ++nt) sacc[nt] = (f32x4){0.f, 0.f, 0.f, 0.f};
        #pragma unroll
        for (int ks = 0; ks < 2; ++ks)
            #pragma unroll
            for (int nt = 0; nt < 4; ++nt)
                sacc[nt] = mfma16(qa[ks], kf[ks][nt], sacc[nt]);

        // p = exp2(C3 * rcp(exp2(arg) + 1)); arg = sacc*Ac + (bd + tb)
        // (fabs dropped: off-diag has qpos>kpos; diag's kpos>qpos is masked)
        const float tb = Bc * (float)(q0 - k0);
        const bool diag = (kt == qt);
        #pragma unroll
        for (int nt = 0; nt < 4; ++nt) {
            #pragma unroll
            for (int reg = 0; reg < 4; ++reg) {
                float arg = fmaf(sacc[nt][reg], Ac, bd[nt][reg] + tb);
                float wv  = exp2f(arg);
                float r   = __builtin_amdgcn_rcpf(wv + 1.0f);
                float pv  = exp2f(r * C3);
                if (diag && (16*nt + l15) > (16*w + 4*quad + reg)) pv = 0.0f;
                lrow[reg] += pv;
                Ps[w][quad*4 + reg][16*nt + l15] = f2bf(pv);
            }
        }

        // PV: wave-private LDS round-trip (DS ops in-order per wave — no barrier)
        #pragma unroll
        for (int ks = 0; ks < 2; ++ks) {
            v8bf pa = *(const v8bf*)&Ps[w][l15][ks*32 + quad*8];
            #pragma unroll
            for (int dt = 0; dt < 4; ++dt)
                o[dt] = mfma16(pa, vf[ks][dt], o[dt]);
        }
    }

    // final: reduce l across the 16-lane row group, normalize, store
    #pragma unroll
    for (int reg = 0; reg < 4; ++reg) {
        #pragma unroll
        for (int off = 1; off < 16; off <<= 1)
            lrow[reg] += __shfl_xor(lrow[reg], off, 64);
    }
    #pragma unroll
    for (int reg = 0; reg < 4; ++reg) {
        int s = q0 + 16*w + quad*4 + reg;
        float inv = 1.0f / lrow[reg];
        #pragma unroll
        for (int dt = 0; dt < 4; ++dt)
            ctx[((size_t)(b*SEQ + s) * NH + h) * DH + 16*dt + l15] = f2bf(o[dt][reg] * inv);
    }
}

// ---------------------------------------------------------------------------
// Kernel 3: out = ctx @ Wo + bo (MFMA). (unchanged, R5-passing)
// ---------------------------------------------------------------------------
__global__ __launch_bounds__(256)
void oproj(const u16* __restrict__ ctx, const u16* __restrict__ wot,
           const u16* __restrict__ bo, const u16* __restrict__ hs_orig,
           void* __restrict__ outp)
{
    __shared__ float red[4];
    __shared__ __align__(16) u16 As[128][72];
    __shared__ __align__(16) u16 Bs[64][72];
    const int tid = threadIdx.x;
    const bool is_f32 = detect_is_f32(hs_orig, tid, red);
    const int w = tid >> 6, lane = tid & 63;
    const int l15 = lane & 15, quad = lane >> 4;
    const int row0 = blockIdx.x * 128;
    const int n0   = blockIdx.y * 64;

    f32x4 acc[2][4];
    #pragma unroll
    for (int mt = 0; mt < 2; ++mt)
        #pragma unroll
        for (int nt = 0; nt < 4; ++nt)
            acc[mt][nt] = (f32x4){0.f, 0.f, 0.f, 0.f};

    for (int k0 = 0; k0 < DMODEL; k0 += 64) {
        __syncthreads();
        #pragma unroll
        for (int it = 0; it < 8; ++it) {
            int e = tid + it * 256;
            int m = e >> 4, k4 = (e & 15) << 2;
            *(ushort4*)&As[m][k4] = *(const ushort4*)(ctx + (size_t)(row0 + m) * DMODEL + k0 + k4);
        }
        #pragma unroll
        for (int it = 0; it < 4; ++it) {
            int e = tid + it * 256;
            int nr = e >> 4, k4 = (e & 15) << 2;
            *(ushort4*)&Bs[nr][k4] = *(const ushort4*)(wot + (size_t)(n0 + nr) * DMODEL + k0 + k4);
        }
        __syncthreads();
        #pragma unroll
        for (int ks = 0; ks < 2; ++ks) {
            v8bf a[2], b[4];
            #pragma unroll
            for (int mt = 0; mt < 2; ++mt)
                a[mt] = *(const v8bf*)&As[32*w + 16*mt + l15][ks*32 + quad*8];
            #pragma unroll
            for (int nt = 0; nt < 4; ++nt)
                b[nt] = *(const v8bf*)&Bs[16*nt + l15][ks*32 + quad*8];
            #pragma unroll
            for (int mt = 0; mt < 2; ++mt)
                #pragma unroll
                for (int nt = 0; nt < 4; ++nt)
                    acc[mt][nt] = mfma16(a[mt], b[nt], acc[mt][nt]);
        }
    }

    #pragma unroll
    for (int mt = 0; mt < 2; ++mt) {
        #pragma unroll
        for (int nt = 0; nt < 4; ++nt) {
            int col = n0 + 16*nt + l15;
            float bias = bf2f(bo[col]);
            #pragma unroll
            for (int reg = 0; reg < 4; ++reg) {
                int row = row0 + 32*w + 16*mt + quad*4 + reg;
                float val = acc[mt][nt][reg] + bias;
                if (is_f32) ((float*)outp)[(size_t)row * DMODEL + col] = val;
                else        ((u16*)outp)[(size_t)row * DMODEL + col]   = f2bf(val);
            }
        }
    }
}

extern "C" void kernel_launch(void* const* d_in, const int* in_sizes, int n_in,
                              void* d_out, int out_size, void* d_ws, size_t ws_size,
                              hipStream_t stream) {
    u16* ws = (u16*)d_ws;
    u16* canon = ws;
    u16* qws = ws + W_Q;
    u16* kws = ws + W_K;
    u16* vws = ws + W_V;
    u16* ctxp = ws + W_CTX;
    float* ropec = (float*)(ws + W_CTX);          // transient, overwritten by ctx
    float* ropes = ropec + SEQ * DH;
    const u16* hs_raw = (const u16*)d_in[0];

    conv_hs_bo<<<dim3(4097), 256, 0, stream>>>(d_in[0], d_in[5], canon);
    transp_w<<<dim3(32, 32), 256, 0, stream>>>(d_in[1], canon + C_WQ, 2048, 2048, hs_raw);
    transp_w<<<dim3(8, 32),  256, 0, stream>>>(d_in[2], canon + C_WK, 2048, 512, hs_raw);
    transp_w<<<dim3(8, 32),  256, 0, stream>>>(d_in[3], canon + C_WV, 2048, 512, hs_raw);
    transp_w<<<dim3(32, 32), 256, 0, stream>>>(d_in[4], canon + C_WO, 2048, 2048, hs_raw);
    rope_table<<<dim3(512), 256, 0, stream>>>(ropec, ropes);
    gemm_qkv<<<dim3(32, 48), 256, 0, stream>>>(canon + C_HS, canon + C_WQ,
        canon + C_WK, canon + C_WV, ropec, ropes, qws, kws, vws);
    attn<<<dim3(SEQ/64, NH, 2), 256, 0, stream>>>(qws, kws, vws, ctxp);
    oproj<<<dim3(32, 32), 256, 0, stream>>>(ctxp, canon + C_WO, canon + C_BO,
        hs_raw, d_out);
}

// Round 8
// 708.337 us; speedup vs baseline: 1.0701x; 1.0701x over previous
//
#include <hip/hip_runtime.h>
#include <hip/hip_bf16.h>
#include <math.h>

#define DMODEL 2048
#define SEQ    2048
#define NH     32
#define NG     8
#define DH     64

typedef unsigned short u16;
using v8bf  = __attribute__((ext_vector_type(8))) __bf16;
using f32x4 = __attribute__((ext_vector_type(4))) float;

__device__ __forceinline__ float bf2f(u16 u) {
    unsigned int x = ((unsigned int)u) << 16;
    return __uint_as_float(x);
}
__device__ __forceinline__ u16 f2bf(float f) {
    unsigned int x = __float_as_uint(f);
    unsigned int r = (x + 0x7fffu + ((x >> 16) & 1u)) >> 16;
    return (u16)r;
}
__device__ __forceinline__ f32x4 mfma16(v8bf a, v8bf b, f32x4 c) {
    return __builtin_amdgcn_mfma_f32_16x16x32_bf16(a, b, c, 0, 0, 0);
}

#define LOG1E4_64 0.14391156509880297f
#define LOG2E     1.4426950408889634f

// ws layout (u16 element offsets). Weights TRANSPOSED [n][k].
// Region reuse over the kernel sequence (footprint = R3-proven 79,695,872 B):
//   [0 .. 8.39M)    hs canon        -> (after gemm_qkv) ctx_acc b=0 (fp32)
//   [8.39M ..12.6M) Wq^T            -> (after gemm_qkv) l_acc (fp32) + slack
//   [12.6M..14.7M)  Wk^T, Wv^T      -> dead after gemm_qkv
//   [14.7M..18.9M)  Wo^T + bo       -> live until oproj
//   [18.9M..31.5M)  Q,K,V           -> live until attn done
//   [31.5M..39.8M)  RoPE table (transient, gemm_qkv) -> ctx_acc b=1 (fp32)
#define C_HS   0u
#define C_WQ   8388608u
#define C_WK   12582912u
#define C_WV   13631488u
#define C_WO   14680064u
#define C_BO   18874368u
#define W_Q    18876416u   // [b,h][s][d]
#define W_K    27265024u   // [b,g][s][d]
#define W_V    29362176u   // [b,g][d][s]
#define W_CTX  31459328u   // ctx_acc b=1 / transient RoPE table

#define CHUNK  4           // kt tiles per attn block
#define NPAIRS 144         // sum over qt of ceil((qt+1)/4)

// ---------------------------------------------------------------------------
// Runtime input-dtype detection (R3-verified).
// ---------------------------------------------------------------------------
__device__ __forceinline__ bool detect_is_f32(const u16* hsu, int tid, float* red)
{
    ushort4 a = *(const ushort4*)(hsu + tid * 8);
    ushort4 b = *(const ushort4*)(hsu + tid * 8 + 4);
    u16 vals[8] = {a.x, a.y, a.z, a.w, b.x, b.y, b.z, b.w};
    float mymax = 0.0f;
    #pragma unroll
    for (int e = 0; e < 8; ++e) {
        float av = fabsf(bf2f(vals[e]));
        if (!(av < 1.0e30f)) av = 1.0e30f;
        mymax = fmaxf(mymax, av);
    }
    #pragma unroll
    for (int off = 1; off < 64; off <<= 1)
        mymax = fmaxf(mymax, __shfl_xor(mymax, off, 64));
    if ((tid & 63) == 0) red[tid >> 6] = mymax;
    __syncthreads();
    float m = fmaxf(fmaxf(red[0], red[1]), fmaxf(red[2], red[3]));
    __syncthreads();
    return m > 1.0e6f;
}

// ---------------------------------------------------------------------------
// Prelude A: convert hs + bo to canonical bf16.
// ---------------------------------------------------------------------------
__global__ __launch_bounds__(256)
void conv_hs_bo(const void* __restrict__ hs, const void* __restrict__ bo,
                u16* __restrict__ canon)
{
    __shared__ float red[4];
    const int tid = threadIdx.x;
    const bool is_f32 = detect_is_f32((const u16*)hs, tid, red);
    unsigned int g = (blockIdx.x * 256u + tid) * 8u;
    const void* src; unsigned int loc; u16* dst;
    if (g < 8388608u) { src = hs; loc = g;            dst = canon + C_HS + g; }
    else              { src = bo; loc = g - 8388608u; dst = canon + C_BO + loc; }

    ushort4 o0, o1;
    if (is_f32) {
        const float* f = (const float*)src + loc;
        float4 x = *(const float4*)f;
        float4 y = *(const float4*)(f + 4);
        o0.x = f2bf(x.x); o0.y = f2bf(x.y); o0.z = f2bf(x.z); o0.w = f2bf(x.w);
        o1.x = f2bf(y.x); o1.y = f2bf(y.y); o1.z = f2bf(y.z); o1.w = f2bf(y.w);
    } else {
        const u16* u = (const u16*)src + loc;
        o0 = *(const ushort4*)u;
        o1 = *(const ushort4*)(u + 4);
    }
    *(ushort4*)dst       = o0;
    *(ushort4*)(dst + 4) = o1;
}

// ---------------------------------------------------------------------------
// Prelude B: tiled transpose-convert of weight (K x N) -> bf16 [n][k].
// ---------------------------------------------------------------------------
__global__ __launch_bounds__(256)
void transp_w(const void* __restrict__ W, u16* __restrict__ dst,
              int K, int N, const u16* __restrict__ hs_orig)
{
    __shared__ float red[4];
    __shared__ u16 Ts[64][68];
    const int tid = threadIdx.x;
    const bool is_f32 = detect_is_f32(hs_orig, tid, red);
    const int n0 = blockIdx.x * 64, k0 = blockIdx.y * 64;

    #pragma unroll
    for (int it = 0; it < 4; ++it) {
        int e  = tid + it * 256;
        int kr = e >> 4, n4 = (e & 15) << 2;
        if (is_f32) {
            const float* s = (const float*)W + (size_t)(k0 + kr) * N + n0 + n4;
            float4 x = *(const float4*)s;
            Ts[n4+0][kr] = f2bf(x.x); Ts[n4+1][kr] = f2bf(x.y);
            Ts[n4+2][kr] = f2bf(x.z); Ts[n4+3][kr] = f2bf(x.w);
        } else {
            ushort4 u = *(const ushort4*)((const u16*)W + (size_t)(k0 + kr) * N + n0 + n4);
            Ts[n4+0][kr] = u.x; Ts[n4+1][kr] = u.y;
            Ts[n4+2][kr] = u.z; Ts[n4+3][kr] = u.w;
        }
    }
    __syncthreads();
    #pragma unroll
    for (int it = 0; it < 4; ++it) {
        int e  = tid + it * 256;
        int nr = e >> 4, k4 = (e & 15) << 2;
        ushort4 u;
        u.x = Ts[nr][k4+0]; u.y = Ts[nr][k4+1];
        u.z = Ts[nr][k4+2]; u.w = Ts[nr][k4+3];
        *(ushort4*)(dst + (size_t)(n0 + nr) * K + k0 + k4) = u;
    }
}

// ---------------------------------------------------------------------------
// Prelude C: RoPE table (precise sincosf; angles to 2047 rad).
// ---------------------------------------------------------------------------
__global__ __launch_bounds__(256)
void rope_table(float* __restrict__ c, float* __restrict__ s)
{
    int idx = blockIdx.x * 256 + threadIdx.x;     // 131072 total
    int sq = idx >> 6, d = idx & 63;
    float freq = expf(-(float)(d & ~1) * LOG1E4_64);
    float sn, cs;
    sincosf((float)sq * freq, &sn, &cs);
    c[idx] = cs; s[idx] = sn;
}

// ---------------------------------------------------------------------------
// Zero the fp32 accumulators (runs AFTER gemm_qkv — regions dead only then).
// Region A: floats [0 .. 4,325,376)  = ctx_acc b0 + l_acc (contiguous).
// Region B: floats [15,729,664 .. 19,923,968) = ctx_acc b1.
// ---------------------------------------------------------------------------
__global__ __launch_bounds__(256)
void zero_acc(float* __restrict__ ws)
{
    const unsigned int nA = 4325376u / 4u;        // float4 count region A
    const unsigned int nB = 4194304u / 4u;        // float4 count region B
    const float4 z = make_float4(0.f, 0.f, 0.f, 0.f);
    for (unsigned int i = blockIdx.x * 256u + threadIdx.x; i < nA + nB;
         i += gridDim.x * 256u) {
        if (i < nA) ((float4*)ws)[i] = z;
        else        ((float4*)(ws + 15729664u))[i - nA] = z;
    }
}

// ---------------------------------------------------------------------------
// Kernel 1: QKV projection (MFMA) + RoPE epilogue. (unchanged, R5-passing)
// ---------------------------------------------------------------------------
__global__ __launch_bounds__(256)
void gemm_qkv(const u16* __restrict__ hs, const u16* __restrict__ wqt,
              const u16* __restrict__ wkt, const u16* __restrict__ wvt,
              const float* __restrict__ ropec, const float* __restrict__ ropes,
              u16* __restrict__ qws, u16* __restrict__ kws, u16* __restrict__ vws)
{
    __shared__ __align__(16) u16 As[128][72];
    __shared__ __align__(16) u16 Bs[64][72];
    const int tid = threadIdx.x;
    const int w = tid >> 6, lane = tid & 63;
    const int l15 = lane & 15, quad = lane >> 4;
    const int row0 = blockIdx.x * 128;
    const int n0   = blockIdx.y * 64;

    const u16* Wt; int nb, mode;
    if (n0 < 2048)      { Wt = wqt; nb = n0;        mode = 0; }
    else if (n0 < 2560) { Wt = wkt; nb = n0 - 2048; mode = 1; }
    else                { Wt = wvt; nb = n0 - 2560; mode = 2; }

    f32x4 acc[2][4];
    #pragma unroll
    for (int mt = 0; mt < 2; ++mt)
        #pragma unroll
        for (int nt = 0; nt < 4; ++nt)
            acc[mt][nt] = (f32x4){0.f, 0.f, 0.f, 0.f};

    for (int k0 = 0; k0 < DMODEL; k0 += 64) {
        __syncthreads();
        #pragma unroll
        for (int it = 0; it < 8; ++it) {
            int e = tid + it * 256;
            int m = e >> 4, k4 = (e & 15) << 2;
            *(ushort4*)&As[m][k4] = *(const ushort4*)(hs + (size_t)(row0 + m) * DMODEL + k0 + k4);
        }
        #pragma unroll
        for (int it = 0; it < 4; ++it) {
            int e = tid + it * 256;
            int nr = e >> 4, k4 = (e & 15) << 2;
            *(ushort4*)&Bs[nr][k4] = *(const ushort4*)(Wt + (size_t)(nb + nr) * DMODEL + k0 + k4);
        }
        __syncthreads();
        #pragma unroll
        for (int ks = 0; ks < 2; ++ks) {
            v8bf a[2], b[4];
            #pragma unroll
            for (int mt = 0; mt < 2; ++mt)
                a[mt] = *(const v8bf*)&As[32*w + 16*mt + l15][ks*32 + quad*8];
            #pragma unroll
            for (int nt = 0; nt < 4; ++nt)
                b[nt] = *(const v8bf*)&Bs[16*nt + l15][ks*32 + quad*8];
            #pragma unroll
            for (int mt = 0; mt < 2; ++mt)
                #pragma unroll
                for (int nt = 0; nt < 4; ++nt)
                    acc[mt][nt] = mfma16(a[mt], b[nt], acc[mt][nt]);
        }
    }

    #pragma unroll
    for (int mt = 0; mt < 2; ++mt) {
        #pragma unroll
        for (int nt = 0; nt < 4; ++nt) {
            int col  = n0 + 16*nt + l15;
            int dcol = col & 63;
            #pragma unroll
            for (int reg = 0; reg < 4; ++reg) {
                int row = row0 + 32*w + 16*mt + quad*4 + reg;
                int b = row >> 11, s = row & (SEQ - 1);
                float val = acc[mt][nt][reg];
                if (mode < 2) {   // RoPE (pairs sit in adjacent lanes)
                    float c2 = ropec[(s << 6) + dcol];
                    float s2 = ropes[(s << 6) + dcol];
                    float partner = __shfl_xor(val, 1, 64);
                    val = (dcol & 1) ? (val * c2 + partner * s2)
                                     : (val * c2 - partner * s2);
                }
                if (mode == 0) {
                    int h = col >> 6;
                    qws[((size_t)((b*NH + h) * SEQ + s)) * DH + dcol] = f2bf(val);
                } else if (mode == 1) {
                    int g = (col - 2048) >> 6;
                    kws[((size_t)((b*NG + g) * SEQ + s)) * DH + dcol] = f2bf(val);
                } else {
                    int g = (col - 2560) >> 6;
                    vws[((size_t)((b*NG + g) * DH + dcol)) * SEQ + s] = f2bf(val);
                }
            }
        }
    }
}

// ---------------------------------------------------------------------------
// Kernel 2: split-K flash attention. Each block = up to CHUNK kt-tiles of one
// (qt, h, b). Fixed-max softmax makes partial (O, l) pure sums -> combined
// with fp32 HW atomics (fire-and-forget, off the critical path). Grid is
// near-uniform in work -> no causal drain tail.
// ---------------------------------------------------------------------------
__global__ __launch_bounds__(256)
void attn(const u16* __restrict__ qws, const u16* __restrict__ kws,
          const u16* __restrict__ vws, float* __restrict__ acc0,
          float* __restrict__ acc1, float* __restrict__ l_acc)
{
    __shared__ __align__(16) u16 Ps[4][16][72];   // wave-private P
    const int tid = threadIdx.x;
    const int w = tid >> 6, lane = tid & 63;
    const int l15 = lane & 15, quad = lane >> 4;

    // decode (qt, chunk) from blockIdx.x: chunks per qt = ceil((qt+1)/CHUNK)
    int p = blockIdx.x, qt = 0;
    while (true) { int nc = (qt + CHUNK) >> 2; if (p < nc) break; p -= nc; ++qt; }
    const int kt_begin = p * CHUNK;
    const int kt_end   = min(kt_begin + CHUNK, qt + 1);   // exclusive

    const int h = blockIdx.y, b = blockIdx.z;
    const int g  = h >> 2;
    const int q0 = qt * 64;

    const float slope = exp2f(-0.25f * (float)(h + 1));
    const u16* qbase  = qws + (size_t)(b*NH + h) * SEQ * DH;
    const u16* kbase  = kws + (size_t)(b*NG + g) * SEQ * DH;
    const u16* vtbase = vws + (size_t)(b*NG + g) * DH * SEQ;   // [d][s]
    float* cacc = b ? acc1 : acc0;

    // Q A-frags in registers: A[m=l15][k=ks*32+quad*8+j], rows q0+16w+l15
    const u16* qrow = qbase + (size_t)(q0 + 16*w + l15) * DH;
    v8bf qa[2];
    qa[0] = *(const v8bf*)(qrow + 0*32 + quad*8);
    qa[1] = *(const v8bf*)(qrow + 1*32 + quad*8);

    const float Ac = 0.125f * (LOG2E / 15.0f);
    const float Bc = -slope * 0.125f * (LOG2E / 15.0f);
    const float C3 = -60.0f * LOG2E;
    float bd[4][4];
    #pragma unroll
    for (int nt = 0; nt < 4; ++nt)
        #pragma unroll
        for (int reg = 0; reg < 4; ++reg)
            bd[nt][reg] = Bc * (float)((16*w + 4*quad + reg) - (16*nt + l15));

    f32x4 o[4];
    #pragma unroll
    for (int dt = 0; dt < 4; ++dt) o[dt] = (f32x4){0.f, 0.f, 0.f, 0.f};
    float lrow[4] = {0.f, 0.f, 0.f, 0.f};

    for (int kt = kt_begin; kt < kt_end; ++kt) {
        const int k0 = kt * 64;

        v8bf kf[2][4], vf[2][4];
        #pragma unroll
        for (int ks = 0; ks < 2; ++ks)
            #pragma unroll
            for (int nt = 0; nt < 4; ++nt)
                kf[ks][nt] = *(const v8bf*)(kbase + (size_t)(k0 + 16*nt + l15) * DH + ks*32 + quad*8);
        #pragma unroll
        for (int ks = 0; ks < 2; ++ks)
            #pragma unroll
            for (int dt = 0; dt < 4; ++dt)
                vf[ks][dt] = *(const v8bf*)(vtbase + (size_t)(16*dt + l15) * SEQ + k0 + ks*32 + quad*8);

        f32x4 sacc[4];
        #pragma unroll
        for (int nt = 0; nt < 4; ++nt) sacc[nt] = (f32x4){0.f, 0.f, 0.f, 0.f};
        #pragma unroll
        for (int ks = 0; ks < 2; ++ks)
            #pragma unroll
            for (int nt = 0; nt < 4; ++nt)
                sacc[nt] = mfma16(qa[ks], kf[ks][nt], sacc[nt]);

        // p = exp2(C3 * rcp(exp2(arg) + 1)); arg = sacc*Ac + (bd + tb)
        const float tb = Bc * (float)(q0 - k0);
        const bool diag = (kt == qt);
        #pragma unroll
        for (int nt = 0; nt < 4; ++nt) {
            #pragma unroll
            for (int reg = 0; reg < 4; ++reg) {
                float arg = fmaf(sacc[nt][reg], Ac, bd[nt][reg] + tb);
                float wv  = exp2f(arg);
                float r   = __builtin_amdgcn_rcpf(wv + 1.0f);
                float pv  = exp2f(r * C3);
                if (diag && (16*nt + l15) > (16*w + 4*quad + reg)) pv = 0.0f;
                lrow[reg] += pv;
                Ps[w][quad*4 + reg][16*nt + l15] = f2bf(pv);
            }
        }

        // PV: wave-private LDS round-trip (DS ops in-order per wave)
        #pragma unroll
        for (int ks = 0; ks < 2; ++ks) {
            v8bf pa = *(const v8bf*)&Ps[w][l15][ks*32 + quad*8];
            #pragma unroll
            for (int dt = 0; dt < 4; ++dt)
                o[dt] = mfma16(pa, vf[ks][dt], o[dt]);
        }
    }

    // combine: l partial -> 16-lane group sum -> one atomic per row;
    // O partial -> 16 atomics per lane (HW global_atomic_add_f32).
    #pragma unroll
    for (int reg = 0; reg < 4; ++reg) {
        float lr = lrow[reg];
        #pragma unroll
        for (int off = 1; off < 16; off <<= 1)
            lr += __shfl_xor(lr, off, 64);
        int s = q0 + 16*w + quad*4 + reg;
        if (l15 == 0)
            unsafeAtomicAdd(l_acc + ((size_t)(b*SEQ + s) * NH + h), lr);
        #pragma unroll
        for (int dt = 0; dt < 4; ++dt)
            unsafeAtomicAdd(cacc + (size_t)s * DMODEL + h*64 + 16*dt + l15, o[dt][reg]);
    }
}

// ---------------------------------------------------------------------------
// Kernel 3: out = (ctx_acc / l) @ Wo + bo. Normalization folded into the
// fp32->bf16 A-staging (k-tile of 64 == one head -> h = k0>>6 is uniform).
// ---------------------------------------------------------------------------
__global__ __launch_bounds__(256)
void oproj(const float* __restrict__ acc0, const float* __restrict__ acc1,
           const float* __restrict__ l_acc, const u16* __restrict__ wot,
           const u16* __restrict__ bo, const u16* __restrict__ hs_orig,
           void* __restrict__ outp)
{
    __shared__ float red[4];
    __shared__ __align__(16) u16 As[128][72];
    __shared__ __align__(16) u16 Bs[64][72];
    const int tid = threadIdx.x;
    const bool is_f32 = detect_is_f32(hs_orig, tid, red);
    const int w = tid >> 6, lane = tid & 63;
    const int l15 = lane & 15, quad = lane >> 4;
    const int row0 = blockIdx.x * 128;
    const int n0   = blockIdx.y * 64;

    f32x4 acc[2][4];
    #pragma unroll
    for (int mt = 0; mt < 2; ++mt)
        #pragma unroll
        for (int nt = 0; nt < 4; ++nt)
            acc[mt][nt] = (f32x4){0.f, 0.f, 0.f, 0.f};

    for (int k0 = 0; k0 < DMODEL; k0 += 64) {
        const int h = k0 >> 6;
        __syncthreads();
        #pragma unroll
        for (int it = 0; it < 8; ++it) {
            int e = tid + it * 256;
            int r = e >> 4, c4 = (e & 15) << 2;
            int row = row0 + r, b = row >> 11, s = row & (SEQ - 1);
            const float* cb = b ? acc1 : acc0;
            float linv = __builtin_amdgcn_rcpf(l_acc[(size_t)(b*SEQ + s) * NH + h]);
            float4 x = *(const float4*)(cb + (size_t)s * DMODEL + k0 + c4);
            As[r][c4+0] = f2bf(x.x * linv); As[r][c4+1] = f2bf(x.y * linv);
            As[r][c4+2] = f2bf(x.z * linv); As[r][c4+3] = f2bf(x.w * linv);
        }
        #pragma unroll
        for (int it = 0; it < 4; ++it) {
            int e = tid + it * 256;
            int nr = e >> 4, k4 = (e & 15) << 2;
            *(ushort4*)&Bs[nr][k4] = *(const ushort4*)(wot + (size_t)(n0 + nr) * DMODEL + k0 + k4);
        }
        __syncthreads();
        #pragma unroll
        for (int ks = 0; ks < 2; ++ks) {
            v8bf a[2], b[4];
            #pragma unroll
            for (int mt = 0; mt < 2; ++mt)
                a[mt] = *(const v8bf*)&As[32*w + 16*mt + l15][ks*32 + quad*8];
            #pragma unroll
            for (int nt = 0; nt < 4; ++nt)
                b[nt] = *(const v8bf*)&Bs[16*nt + l15][ks*32 + quad*8];
            #pragma unroll
            for (int mt = 0; mt < 2; ++mt)
                #pragma unroll
                for (int nt = 0; nt < 4; ++nt)
                    acc[mt][nt] = mfma16(a[mt], b[nt], acc[mt][nt]);
        }
    }

    #pragma unroll
    for (int mt = 0; mt < 2; ++mt) {
        #pragma unroll
        for (int nt = 0; nt < 4; ++nt) {
            int col = n0 + 16*nt + l15;
            float bias = bf2f(bo[col]);
            #pragma unroll
            for (int reg = 0; reg < 4; ++reg) {
                int row = row0 + 32*w + 16*mt + quad*4 + reg;
                float val = acc[mt][nt][reg] + bias;
                if (is_f32) ((float*)outp)[(size_t)row * DMODEL + col] = val;
                else        ((u16*)outp)[(size_t)row * DMODEL + col]   = f2bf(val);
            }
        }
    }
}

extern "C" void kernel_launch(void* const* d_in, const int* in_sizes, int n_in,
                              void* d_out, int out_size, void* d_ws, size_t ws_size,
                              hipStream_t stream) {
    u16* ws = (u16*)d_ws;
    u16* canon = ws;
    u16* qws = ws + W_Q;
    u16* kws = ws + W_K;
    u16* vws = ws + W_V;
    float* ropec = (float*)(ws + W_CTX);          // transient
    float* ropes = ropec + SEQ * DH;
    float* acc0  = (float*)ws;                    // reuses hs canon (dead after gemm_qkv)
    float* acc1  = (float*)(ws + W_CTX);          // reuses rope region
    float* l_acc = (float*)(ws + C_WQ);           // reuses Wq^T (dead after gemm_qkv)
    const u16* hs_raw = (const u16*)d_in[0];

    conv_hs_bo<<<dim3(4097), 256, 0, stream>>>(d_in[0], d_in[5], canon);
    transp_w<<<dim3(32, 32), 256, 0, stream>>>(d_in[1], canon + C_WQ, 2048, 2048, hs_raw);
    transp_w<<<dim3(8, 32),  256, 0, stream>>>(d_in[2], canon + C_WK, 2048, 512, hs_raw);
    transp_w<<<dim3(8, 32),  256, 0, stream>>>(d_in[3], canon + C_WV, 2048, 512, hs_raw);
    transp_w<<<dim3(32, 32), 256, 0, stream>>>(d_in[4], canon + C_WO, 2048, 2048, hs_raw);
    rope_table<<<dim3(512), 256, 0, stream>>>(ropec, ropes);
    gemm_qkv<<<dim3(32, 48), 256, 0, stream>>>(canon + C_HS, canon + C_WQ,
        canon + C_WK, canon + C_WV, ropec, ropes, qws, kws, vws);
    zero_acc<<<dim3(2048), 256, 0, stream>>>((float*)ws);
    attn<<<dim3(NPAIRS, NH, 2), 256, 0, stream>>>(qws, kws, vws, acc0, acc1, l_acc);
    oproj<<<dim3(32, 32), 256, 0, stream>>>(acc0, acc1, l_acc,
        canon + C_WO, canon + C_BO, hs_raw, d_out);
}